// Round 1
// baseline (498.402 us; speedup 1.0000x reference)
//
#include <hip/hip_runtime.h>

// Problem: B=16, C=1, H=2048, W=2048 fp32.
// out = a0*x + a1*(left+right) + a2*(up+down)   (replicate-padded 5-pt stencil)
//     + w0 + w1*x + w2*x^2 + w3*x^3             (Horner, CONST=0)
//
// Memory-bound: 256 MB in + 256 MB out. One thread per float4.

#define H_DIM 2048
#define W_DIM 2048
#define W4    (W_DIM / 4)   // 512 float4 per row

__global__ __launch_bounds__(256) void FCNN_63651415326860_kernel(
    const float* __restrict__ x,
    const float* __restrict__ a,
    const float* __restrict__ w,
    float* __restrict__ out)
{
    const int v = blockIdx.x * blockDim.x + threadIdx.x;   // float4 index
    const int col4 = v & (W4 - 1);          // float4 column within row
    const int rowg = v >> 9;                // global row across B*H (W4 = 2^9)
    const int row  = rowg & (H_DIM - 1);    // row within one image

    const float4* x4 = (const float4*)x;

    const float4 c  = x4[v];
    const float4 up = (row == 0)         ? c : x4[v - W4];
    const float4 dn = (row == H_DIM - 1) ? c : x4[v + W4];

    // horizontal edge neighbors (scalar loads; same cache lines as neighbor threads)
    const float leftN  = (col4 == 0)      ? c.x : x[(size_t)v * 4 - 1];
    const float rightN = (col4 == W4 - 1) ? c.w : x[(size_t)v * 4 + 4];

    // broadcast scalars (uniform address -> scalar loads, cached)
    const float a0 = a[0], a1 = a[1], a2 = a[2];
    const float w0 = w[0], w1 = w[1], w2 = w[2], w3 = w[3];

    float4 r;
    {
        const float h  = leftN + c.y;
        const float vv = up.x + dn.x;
        const float s  = a0 * c.x + a1 * h + a2 * vv;
        const float p  = fmaf(fmaf(fmaf(w3, c.x, w2), c.x, w1), c.x, w0);
        r.x = s + p;
    }
    {
        const float h  = c.x + c.z;
        const float vv = up.y + dn.y;
        const float s  = a0 * c.y + a1 * h + a2 * vv;
        const float p  = fmaf(fmaf(fmaf(w3, c.y, w2), c.y, w1), c.y, w0);
        r.y = s + p;
    }
    {
        const float h  = c.y + c.w;
        const float vv = up.z + dn.z;
        const float s  = a0 * c.z + a1 * h + a2 * vv;
        const float p  = fmaf(fmaf(fmaf(w3, c.z, w2), c.z, w1), c.z, w0);
        r.z = s + p;
    }
    {
        const float h  = c.z + rightN;
        const float vv = up.w + dn.w;
        const float s  = a0 * c.w + a1 * h + a2 * vv;
        const float p  = fmaf(fmaf(fmaf(w3, c.w, w2), c.w, w1), c.w, w0);
        r.w = s + p;
    }

    ((float4*)out)[v] = r;
}

extern "C" void kernel_launch(void* const* d_in, const int* in_sizes, int n_in,
                              void* d_out, int out_size, void* d_ws, size_t ws_size,
                              hipStream_t stream) {
    const float* x = (const float*)d_in[0];   // 16*1*2048*2048 fp32
    const float* a = (const float*)d_in[1];   // 3 fp32
    const float* w = (const float*)d_in[2];   // 4 fp32
    float* out = (float*)d_out;

    const int total4 = out_size / 4;          // 16,777,216 float4s
    const int block = 256;
    const int grid = total4 / block;          // 65,536 blocks

    FCNN_63651415326860_kernel<<<grid, block, 0, stream>>>(x, a, w, out);
}